// Round 9
// baseline (307.544 us; speedup 1.0000x reference)
//
#include <hip/hip_runtime.h>
#include <math.h>

#define BB 8
#define LL 2048
#define DD 512
#define HH 8
#define DHH 64
#define KD 8
#define MM (BB*LL)   // 16384

typedef _Float16 f16x4 __attribute__((ext_vector_type(4)));
typedef _Float16 f16x8 __attribute__((ext_vector_type(8)));
typedef float    f32x4 __attribute__((ext_vector_type(4)));

// ---------------- prep: fp32 -> fp16 hi/lo (x and W fused in one launch) ----------------
__device__ inline void cvt8(const float* __restrict__ s, _Float16* hp, _Float16* lp) {
    const float4 a = *(const float4*)s;
    const float4 b = *(const float4*)(s + 4);
    const float v[8] = {a.x, a.y, a.z, a.w, b.x, b.y, b.z, b.w};
    f16x8 hi, lo;
#pragma unroll
    for (int j = 0; j < 8; j++) {
        const _Float16 h = (_Float16)v[j];
        hi[j] = h;
        lo[j] = (_Float16)((v[j] - (float)h) * 512.0f);
    }
    *(f16x8*)hp = hi;
    if (lp) *(f16x8*)lp = lo;
}

__global__ __launch_bounds__(256) void prep_all(const float* __restrict__ xq,
                                                const float* __restrict__ xkv,
                                                const float* __restrict__ Wq, const float* __restrict__ Wk,
                                                const float* __restrict__ Wv, const float* __restrict__ Wo,
                                                _Float16* __restrict__ Xq_h, _Float16* __restrict__ Xq_l,
                                                _Float16* __restrict__ Xkv_h, _Float16* __restrict__ Xkv_l,
                                                _Float16* __restrict__ Wq_h, _Float16* __restrict__ Wq_l,
                                                _Float16* __restrict__ Wk_h, _Float16* __restrict__ Wk_l,
                                                _Float16* __restrict__ Wv_h, _Float16* __restrict__ Wo_h) {
    const int bid = blockIdx.x;
    if (bid < 8192) {   // x_q / x_kv: 2097152 threads × 8 elems
        const int g = bid * 256 + threadIdx.x;
        const int which = g >> 20;
        const size_t idx = (size_t)(g & 1048575) * 8;
        const float* src = which ? xkv : xq;
        _Float16* dh = which ? Xkv_h : Xq_h;
        _Float16* dl = which ? Xkv_l : Xq_l;
        cvt8(src + idx, dh + idx, dl + idx);
    } else {            // weights: 131072 threads × 8 elems
        const int g = (bid - 8192) * 256 + threadIdx.x;
        const int which = g >> 15;
        const size_t idx = (size_t)(g & 32767) * 8;
        if (which == 0)      cvt8(Wq + idx, Wq_h + idx, Wq_l + idx);
        else if (which == 1) cvt8(Wk + idx, Wk_h + idx, Wk_l + idx);
        else if (which == 2) cvt8(Wv + idx, Wv_h + idx, nullptr);
        else                 cvt8(Wo + idx, Wo_h + idx, nullptr);
    }
}

// ---------------- MFMA GEMM body: C = A @ B^T + bias ----------------
// NPROD==1: plain (hi only). NPROD==3: hi/lo split (score path).
// MODE 0: fp32 C[m*512+n]
// MODE 1: fp32 C[(b*512+n)*2048+l]   (score path stays fp32 in storage)
// MODE 2: fp16 v-layout C[b,h,l,dh]
template<int NPROD, int MODE>
__device__ __forceinline__ void gemm_body(const _Float16* __restrict__ Ag,
                                          const _Float16* __restrict__ Al_g,
                                          const _Float16* __restrict__ Bg,
                                          const _Float16* __restrict__ Bl_g,
                                          const float* __restrict__ bias,
                                          void* __restrict__ Cv,
                                          _Float16* lds, int l0) {
    _Float16* Ah = lds;            // [128][40] halves, padded row stride
    _Float16* Bh = lds + 5120;
    _Float16* Al = (NPROD == 3) ? lds + 10240 : lds;
    _Float16* Bl = (NPROD == 3) ? lds + 15360 : lds;

    const int t  = threadIdx.x;
    const int m0 = (((l0 >> 5) << 3) | (l0 & 7)) * 128;   // XCD swizzle: 4 n-tiles/m-tile per XCD
    const int n0 = ((l0 >> 3) & 3) * 128;

    const int lrow = t >> 2;        // 0..63
    const int lcol = (t & 3) * 8;   // 0,8,16,24
    const int wave = t >> 6;
    const int lane = t & 63;
    const int wm   = (wave >> 1) * 64;
    const int wn   = (wave & 1) * 64;
    const int lm   = lane & 15;
    const int quad = lane >> 4;

    f32x4 acc0[4][4] = {};
    f32x4 acc1[4][4] = {};

    f16x8 pa[2], pb[2], pal[2], pbl[2];
#pragma unroll
    for (int p = 0; p < 2; p++) {
        pa[p] = *(const f16x8*)(Ag + (size_t)(m0 + p * 64 + lrow) * 512 + lcol);
        pb[p] = *(const f16x8*)(Bg + (size_t)(n0 + p * 64 + lrow) * 512 + lcol);
        if (NPROD == 3) {
            pal[p] = *(const f16x8*)(Al_g + (size_t)(m0 + p * 64 + lrow) * 512 + lcol);
            pbl[p] = *(const f16x8*)(Bl_g + (size_t)(n0 + p * 64 + lrow) * 512 + lcol);
        }
    }

    for (int k0 = 0; k0 < 512; k0 += 32) {
        __syncthreads();
#pragma unroll
        for (int p = 0; p < 2; p++) {
            const int row = p * 64 + lrow;
            *(f16x8*)&Ah[row * 40 + lcol] = pa[p];
            *(f16x8*)&Bh[row * 40 + lcol] = pb[p];
            if (NPROD == 3) {
                *(f16x8*)&Al[row * 40 + lcol] = pal[p];
                *(f16x8*)&Bl[row * 40 + lcol] = pbl[p];
            }
        }
        __syncthreads();

        if (k0 + 32 < 512) {
            const int kn = k0 + 32;
#pragma unroll
            for (int p = 0; p < 2; p++) {
                pa[p] = *(const f16x8*)(Ag + (size_t)(m0 + p * 64 + lrow) * 512 + kn + lcol);
                pb[p] = *(const f16x8*)(Bg + (size_t)(n0 + p * 64 + lrow) * 512 + kn + lcol);
                if (NPROD == 3) {
                    pal[p] = *(const f16x8*)(Al_g + (size_t)(m0 + p * 64 + lrow) * 512 + kn + lcol);
                    pbl[p] = *(const f16x8*)(Bl_g + (size_t)(n0 + p * 64 + lrow) * 512 + kn + lcol);
                }
            }
        }

        f16x8 afh[4], bf[4];
#pragma unroll
        for (int mt = 0; mt < 4; mt++)
            afh[mt] = *(f16x8*)&Ah[(wm + mt * 16 + lm) * 40 + quad * 8];
#pragma unroll
        for (int nt = 0; nt < 4; nt++)
            bf[nt] = *(f16x8*)&Bh[(wn + nt * 16 + lm) * 40 + quad * 8];

#pragma unroll
        for (int mt = 0; mt < 4; mt++)
#pragma unroll
            for (int nt = 0; nt < 4; nt++)
                acc0[mt][nt] = __builtin_amdgcn_mfma_f32_16x16x32_f16(afh[mt], bf[nt], acc0[mt][nt], 0, 0, 0);

        if (NPROD == 3) {
            f16x8 afl[4];
#pragma unroll
            for (int mt = 0; mt < 4; mt++)
                afl[mt] = *(f16x8*)&Al[(wm + mt * 16 + lm) * 40 + quad * 8];
#pragma unroll
            for (int mt = 0; mt < 4; mt++)
#pragma unroll
                for (int nt = 0; nt < 4; nt++)
                    acc1[mt][nt] = __builtin_amdgcn_mfma_f32_16x16x32_f16(afl[mt], bf[nt], acc1[mt][nt], 0, 0, 0);
#pragma unroll
            for (int nt = 0; nt < 4; nt++)
                bf[nt] = *(f16x8*)&Bl[(wn + nt * 16 + lm) * 40 + quad * 8];
#pragma unroll
            for (int mt = 0; mt < 4; mt++)
#pragma unroll
                for (int nt = 0; nt < 4; nt++)
                    acc1[mt][nt] = __builtin_amdgcn_mfma_f32_16x16x32_f16(afh[mt], bf[nt], acc1[mt][nt], 0, 0, 0);
        }
    }

    // epilogue: C/D layout col=lane&15, row=quad*4+reg
#pragma unroll
    for (int mt = 0; mt < 4; mt++) {
#pragma unroll
        for (int nt = 0; nt < 4; nt++) {
            const int n = n0 + wn + nt * 16 + lm;
            const float bv = bias[n];
            float val[4];
#pragma unroll
            for (int r = 0; r < 4; r++) {
                val[r] = acc0[mt][nt][r] + bv;
                if (NPROD == 3) val[r] += acc1[mt][nt][r] * (1.0f / 512.0f);
            }
            const int mbase = m0 + wm + mt * 16 + quad * 4;   // multiple of 4
            const int b_idx = mbase >> 11;
            const int lbase = mbase & 2047;
            if (MODE == 0) {
                float* C = (float*)Cv;
#pragma unroll
                for (int r = 0; r < 4; r++) C[(size_t)(mbase + r) * 512 + n] = val[r];
            } else if (MODE == 1) {
                float* C = (float*)Cv;
                float4 pv = make_float4(val[0], val[1], val[2], val[3]);
                *(float4*)&C[((size_t)(b_idx * 512 + n)) * 2048 + lbase] = pv;
            } else {
                _Float16* C = (_Float16*)Cv;
#pragma unroll
                for (int r = 0; r < 4; r++)
                    C[(size_t)b_idx * 1048576 + (size_t)(n >> 6) * 131072
                      + (size_t)(lbase + r) * 64 + (n & 63)] = (_Float16)val[r];
            }
        }
    }
}

// merged q+k projection: 1024 blocks; 0-511 = q, 512-1023 = k (disjoint outputs)
__global__ __launch_bounds__(256, 2) void gemm_qk(const _Float16* __restrict__ A0h, const _Float16* __restrict__ A0l,
                                                  const _Float16* __restrict__ B0h, const _Float16* __restrict__ B0l,
                                                  const float* __restrict__ bias0, float* __restrict__ C0,
                                                  const _Float16* __restrict__ A1h, const _Float16* __restrict__ A1l,
                                                  const _Float16* __restrict__ B1h, const _Float16* __restrict__ B1l,
                                                  const float* __restrict__ bias1, float* __restrict__ C1) {
    __shared__ __align__(16) _Float16 lds[20480];
    const int prob = blockIdx.x >> 9;
    const int l0   = blockIdx.x & 511;
    if (prob == 0)
        gemm_body<3, 1>(A0h, A0l, B0h, B0l, bias0, C0, lds, l0);
    else
        gemm_body<3, 1>(A1h, A1l, B1h, B1l, bias1, C1, lds, l0);
}

__global__ __launch_bounds__(256, 2) void gemm_o(const _Float16* __restrict__ Ah_g,
                                                 const _Float16* __restrict__ Bh_g,
                                                 const float* __restrict__ bias,
                                                 float* __restrict__ C) {
    __shared__ __align__(16) _Float16 lds[10240];
    gemm_body<1, 0>(Ah_g, Ah_g, Bh_g, Bh_g, bias, C, lds, blockIdx.x);
}

// ============== register-resident radix-8 DIF forward FFT (N=2048), fp32 in ==============
// 1024 blocks × 4 sequences. Product accumulator in registers. PAD3 keeps every
// exchange pattern at the b64 bank floor.
#define PAD3(i) ((i) + ((i) >> 3))

__device__ inline float2 cmul2(float2 a, float2 w) {
    return make_float2(a.x * w.x - a.y * w.y, a.x * w.y + a.y * w.x);
}
__device__ inline float2 cadd2(float2 a, float2 b) { return make_float2(a.x + b.x, a.y + b.y); }
__device__ inline float2 csub2(float2 a, float2 b) { return make_float2(a.x - b.x, a.y - b.y); }

__global__ __launch_bounds__(256) void fft_fwd(const float* __restrict__ qT,
                                               const float* __restrict__ kT,
                                               float* __restrict__ specP) {
    const int blk  = blockIdx.x;     // bh*16 + part
    const int bh   = blk >> 4;
    const int part = blk & 15;
    const int t    = threadIdx.x;
    __shared__ float2 Zs[2304];      // PAD3(2047) = 2302
    __shared__ float2 Wt[1024];      // Wt[j] = exp(-2*pi*i*j/2048)

#pragma unroll
    for (int s = 0; s < 4; s++) {
        const int j = t + s * 256;
        float sv, cv;
        __sincosf(2.0f * (float)M_PI * (float)j / 2048.0f, &sv, &cv);
        Wt[j] = make_float2(cv, -sv);
    }

    float2 pacc[8];
#pragma unroll
    for (int s = 0; s < 8; s++) pacc[s] = make_float2(0.0f, 0.0f);

    const int low5 = t & 31, hi3 = t >> 5;
    const int low2 = t & 3,  hi6 = t >> 2;

    for (int j4 = 0; j4 < 4; j4++) {
        const int seq = bh * 64 + part * 4 + j4;
        const float* qp = qT + (size_t)seq * 2048;
        const float* kp = kT + (size_t)seq * 2048;
        float2 z[8];
#pragma unroll
        for (int s = 0; s < 8; s++) z[s] = make_float2(qp[t + 256 * s], kp[t + 256 * s]);
        __syncthreads();   // Wt ready (iter 0); prev unpack reads done (iter >0)

        // round 1 (bits 10,9,8), jb = t
#pragma unroll
        for (int sp = 0; sp < 4; sp++) {
            float2 u = z[sp], v = z[sp + 4];
            z[sp]     = cadd2(u, v);
            z[sp + 4] = cmul2(csub2(u, v), Wt[t + 256 * sp]);
        }
#pragma unroll
        for (int base = 0; base < 8; base += 4)
#pragma unroll
            for (int q2 = 0; q2 < 2; q2++) {
                float2 u = z[base + q2], v = z[base + q2 + 2];
                z[base + q2]     = cadd2(u, v);
                z[base + q2 + 2] = cmul2(csub2(u, v), Wt[2 * (t + 256 * q2)]);
            }
        {
            const float2 w = Wt[4 * t];
#pragma unroll
            for (int e = 0; e < 8; e += 2) {
                float2 u = z[e], v = z[e + 1];
                z[e]     = cadd2(u, v);
                z[e + 1] = cmul2(csub2(u, v), w);
            }
        }

        // exchange 1: (t+256s) -> (low5+32s+256hi3)
#pragma unroll
        for (int s = 0; s < 8; s++) Zs[PAD3(t + 256 * s)] = z[s];
        __syncthreads();
#pragma unroll
        for (int s = 0; s < 8; s++) z[s] = Zs[PAD3(low5 + 32 * s + 256 * hi3)];
        // no barrier: round-2 writes return to the same slots this thread read

        // round 2 (bits 7,6,5), jb = low5
#pragma unroll
        for (int sp = 0; sp < 4; sp++) {
            float2 u = z[sp], v = z[sp + 4];
            z[sp]     = cadd2(u, v);
            z[sp + 4] = cmul2(csub2(u, v), Wt[8 * (low5 + 32 * sp)]);
        }
#pragma unroll
        for (int base = 0; base < 8; base += 4)
#pragma unroll
            for (int q2 = 0; q2 < 2; q2++) {
                float2 u = z[base + q2], v = z[base + q2 + 2];
                z[base + q2]     = cadd2(u, v);
                z[base + q2 + 2] = cmul2(csub2(u, v), Wt[16 * (low5 + 32 * q2)]);
            }
        {
            const float2 w = Wt[32 * low5];
#pragma unroll
            for (int e = 0; e < 8; e += 2) {
                float2 u = z[e], v = z[e + 1];
                z[e]     = cadd2(u, v);
                z[e + 1] = cmul2(csub2(u, v), w);
            }
        }

        // exchange 2: (low5+32s+256hi3) -> (low2+4s+32hi6)
#pragma unroll
        for (int s = 0; s < 8; s++) Zs[PAD3(low5 + 32 * s + 256 * hi3)] = z[s];
        __syncthreads();
#pragma unroll
        for (int s = 0; s < 8; s++) z[s] = Zs[PAD3(low2 + 4 * s + 32 * hi6)];

        // round 3 (bits 4,3,2), jb = low2
#pragma unroll
        for (int sp = 0; sp < 4; sp++) {
            float2 u = z[sp], v = z[sp + 4];
            z[sp]     = cadd2(u, v);
            z[sp + 4] = cmul2(csub2(u, v), Wt[64 * (low2 + 4 * sp)]);
        }
#pragma unroll
        for (int base = 0; base < 8; base += 4)
#pragma unroll
            for (int q2 = 0; q2 < 2; q2++) {
                float2 u = z[base + q2], v = z[base + q2 + 2];
                z[base + q2]     = cadd2(u, v);
                z[base + q2 + 2] = cmul2(csub2(u, v), Wt[128 * (low2 + 4 * q2)]);
            }
        {
            const float2 w = Wt[256 * low2];
#pragma unroll
            for (int e = 0; e < 8; e += 2) {
                float2 u = z[e], v = z[e + 1];
                z[e]     = cadd2(u, v);
                z[e + 1] = cmul2(csub2(u, v), w);
            }
        }

        // exchange 3: (low2+4s+32hi6) -> (8t+s)
#pragma unroll
        for (int s = 0; s < 8; s++) Zs[PAD3(low2 + 4 * s + 32 * hi6)] = z[s];
        __syncthreads();
#pragma unroll
        for (int s = 0; s < 8; s++) z[s] = Zs[PAD3(8 * t + s)];

        // round 4 (bits 1,0)
#pragma unroll
        for (int base = 0; base < 8; base += 4) {
            {
                float2 u = z[base], v = z[base + 2];
                z[base]     = cadd2(u, v);
                z[base + 2] = csub2(u, v);
            }
            {
                float2 u = z[base + 1], v = z[base + 3];
                float2 d = csub2(u, v);
                z[base + 1] = cadd2(u, v);
                z[base + 3] = make_float2(d.y, -d.x);
            }
        }
#pragma unroll
        for (int e = 0; e < 8; e += 2) {
            float2 u = z[e], v = z[e + 1];
            z[e]     = cadd2(u, v);
            z[e + 1] = csub2(u, v);
        }

        // write back completed FFT (same slots this thread read -> only one barrier)
#pragma unroll
        for (int s = 0; s < 8; s++) Zs[PAD3(8 * t + s)] = z[s];
        __syncthreads();

        // unpack q+ik; accumulate P at thread-fixed positions p = t+256s (registers)
#pragma unroll
        for (int s = 0; s < 8; s++) {
            const int p  = t + 256 * s;
            const int f  = (int)(__brev((unsigned)p) >> 21);
            const int fm = (2048 - f) & 2047;
            const int p2 = (int)(__brev((unsigned)fm) >> 21);
            const float2 zf = Zs[PAD3(p)];
            const float2 zm = Zs[PAD3(p2)];
            const float qr = 0.5f * (zf.x + zm.x);
            const float qi = 0.5f * (zf.y - zm.y);
            const float kr = 0.5f * (zf.y + zm.y);
            const float ki = 0.5f * (zm.x - zf.x);
            if (f != 0) {   // DC bin stays zero (mean subtraction)
                pacc[s].x += qr * kr + qi * ki;
                pacc[s].y += qi * kr - qr * ki;
            }
        }
    }

    // one coalesced partial-spectrum store (bit-rev position order)
    float2* outp = (float2*)specP + (size_t)blk * 2048;
#pragma unroll
    for (int s = 0; s < 8; s++) outp[t + 256 * s] = pacc[s];
}

// ---------------- inverse (DIT over bit-reversed input) + top-8, as device fn ----------------
__device__ inline void fft2048_stages(float2* Z, const float2* Wt, int tid) {
    for (int st = 0; st < 11; st++) {
        const int half = 1 << st;
        const int shift = 10 - st;
#pragma unroll
        for (int r = 0; r < 4; r++) {
            const int m   = tid + r * 256;
            const int grp = m >> st;
            const int pos = m & (half - 1);
            const int i0  = (grp << (st + 1)) + pos;
            const int i1  = i0 + half;
            const float2 w = Wt[pos << shift];
            const float2 a = Z[i0];
            const float2 b = Z[i1];
            const float tr = b.x * w.x - b.y * w.y;
            const float ti = b.x * w.y + b.y * w.x;
            Z[i0] = make_float2(a.x + tr, a.y + ti);
            Z[i1] = make_float2(a.x - tr, a.y - ti);
        }
        __syncthreads();
    }
}

__device__ void inv_topk_body(const float* __restrict__ specP,
                              int* __restrict__ delays,
                              float* __restrict__ weights,
                              char* smem, int bh) {
    const int tid = threadIdx.x;
    float2* Z     = (float2*)smem;                 // 2048 * 8 B
    float2* Wt    = Z + 2048;                      // 1024 * 8 B
    float*  corrS = (float*)(Wt + 1024);           // 2048 * 4 B
    float*  rv    = corrS + 2048;                  // 256 * 4 B
    int*    ri    = (int*)(rv + 256);              // 256 * 4 B
    float*  vals  = (float*)(ri + 256);            // 8
    int*    inds  = (int*)(vals + KD);             // 8

#pragma unroll
    for (int s = 0; s < 4; s++) {
        const int j = tid + s * 256;
        float sv, cv;
        __sincosf(2.0f * (float)M_PI * (float)j / 2048.0f, &sv, &cv);
        Wt[j] = make_float2(cv, sv);               // +1 sign (inverse)
    }

    const float2* sp = (const float2*)specP + (size_t)bh * 16 * 2048;
#pragma unroll
    for (int s = 0; s < 8; s++) {
        const int p = tid + s * 256;
        float2 acc = make_float2(0.0f, 0.0f);
#pragma unroll
        for (int part = 0; part < 16; part++) {
            const float2 v = sp[part * 2048 + p];
            acc.x += v.x; acc.y += v.y;
        }
        Z[p] = acc;
    }
    __syncthreads();
    fft2048_stages(Z, Wt, tid);

    const float scale = 1.0f / (2048.0f * 64.0f);
#pragma unroll
    for (int s = 0; s < 8; s++) {
        const int i = tid + s * 256;
        corrS[i] = Z[i].x * scale;
    }
    __syncthreads();

    for (int k = 0; k < KD; k++) {
        float best = -1e30f;
        int   bi   = 1 << 30;
        for (int i = tid; i < 2048; i += 256) {
            const float v = corrS[i];
            if (v > best || (v == best && i < bi)) { best = v; bi = i; }
        }
        rv[tid] = best;
        ri[tid] = bi;
        __syncthreads();
        for (int off = 128; off > 0; off >>= 1) {
            if (tid < off) {
                const float v2 = rv[tid + off];
                const int   i2 = ri[tid + off];
                if (v2 > rv[tid] || (v2 == rv[tid] && i2 < ri[tid])) {
                    rv[tid] = v2; ri[tid] = i2;
                }
            }
            __syncthreads();
        }
        if (tid == 0) {
            vals[k] = rv[0];
            inds[k] = ri[0];
            corrS[ri[0]] = -1e30f;
        }
        __syncthreads();
    }

    if (tid == 0) {
        float sum = 0.0f;
        for (int k = 0; k < KD; k++) sum += vals[k];
        const float inv = 1.0f / (sum + 1e-12f);
        for (int k = 0; k < KD; k++) {
            weights[bh * KD + k] = vals[k] * inv;
            delays[bh * KD + k]  = inds[k];
        }
    }
}

// merged: blocks 0-511 = v-projection GEMM, blocks 512-575 = inverse+top-8
__global__ __launch_bounds__(256, 2) void inv_and_v(const float* __restrict__ specP,
                                                    int* __restrict__ delays,
                                                    float* __restrict__ weights,
                                                    const _Float16* __restrict__ Xkv_h,
                                                    const _Float16* __restrict__ Wv_h,
                                                    const float* __restrict__ bv,
                                                    _Float16* __restrict__ vh) {
    __shared__ __align__(16) char smem[34880];   // max(inv 34880 B, gemm 20480 B)
    if (blockIdx.x < 512)
        gemm_body<1, 2>(Xkv_h, Xkv_h, Wv_h, Wv_h, bv, vh, (_Float16*)smem, blockIdx.x);
    else
        inv_topk_body(specP, delays, weights, smem, blockIdx.x - 512);
}

// weighted circular-shift gather, fp16 in/out, 8 dh per thread (16B loads/stores)
__global__ __launch_bounds__(256) void gather_ws(const _Float16* __restrict__ v,
                                                 const int* __restrict__ delays,
                                                 const float* __restrict__ weights,
                                                 _Float16* __restrict__ outb) {
    const int gp = blockIdx.x * 256 + threadIdx.x;   // over M*64 = 1048576
    const int c8 = gp & 63;
    const int m  = gp >> 6;
    const int l  = m & 2047;
    const int b  = m >> 11;
    const int ch = c8 * 8;
    const int h  = ch >> 6;
    const int dh = ch & 63;
    const int bh = b * 8 + h;

    const _Float16* vb = v + (size_t)bh * 131072;
    float a[8] = {};
#pragma unroll
    for (int k = 0; k < KD; k++) {
        const int   d = delays[bh * KD + k];
        const float w = weights[bh * KD + k];
        const int   p = (l + d) & 2047;
        const f16x8 pv = *(const f16x8*)&vb[p * 64 + dh];
#pragma unroll
        for (int j = 0; j < 8; j++) a[j] = fmaf(w, (float)pv[j], a[j]);
    }
    f16x8 ov;
#pragma unroll
    for (int j = 0; j < 8; j++) ov[j] = (_Float16)a[j];
    *(f16x8*)&outb[(size_t)m * 512 + ch] = ov;
}

extern "C" void kernel_launch(void* const* d_in, const int* in_sizes, int n_in,
                              void* d_out, int out_size, void* d_ws, size_t ws_size,
                              hipStream_t stream) {
    const float* x_q  = (const float*)d_in[0];
    const float* x_kv = (const float*)d_in[1];
    const float* Wq   = (const float*)d_in[2];
    const float* bq   = (const float*)d_in[3];
    const float* Wk   = (const float*)d_in[4];
    const float* bk   = (const float*)d_in[5];
    const float* Wv   = (const float*)d_in[6];
    const float* bv   = (const float*)d_in[7];
    const float* Wo   = (const float*)d_in[8];
    const float* bo   = (const float*)d_in[9];
    float* out = (float*)d_out;

    // ---- workspace layout: d_ws is 256 MiB (fill counter evidence, round 8);
    //      fully unaliased plan, peak use 156 MiB ----
    char* ws = (char*)d_ws;
    _Float16* Xq_h  = (_Float16*)(ws + 0);            // 16 MiB
    _Float16* Xq_l  = (_Float16*)(ws + 16777216);     // 16 MiB
    _Float16* Xkv_h = (_Float16*)(ws + 33554432);     // 16 MiB
    _Float16* Xkv_l = (_Float16*)(ws + 50331648);     // 16 MiB
    _Float16* Wq_h  = (_Float16*)(ws + 67108864);     // 512 KiB each
    _Float16* Wq_l  = (_Float16*)(ws + 67633152);
    _Float16* Wk_h  = (_Float16*)(ws + 68157440);
    _Float16* Wk_l  = (_Float16*)(ws + 68681728);
    _Float16* Wv_h  = (_Float16*)(ws + 69206016);
    _Float16* Wo_h  = (_Float16*)(ws + 69730304);
    int*      dely  = (int*)    (ws + 70254592);
    float*    wgt   = (float*)  (ws + 70256640);
    float*    kf32  = (float*)  (ws + 75497472);      // 32 MiB, disjoint from all GEMM inputs
    float*    specP = (float*)  (ws + 113246208);     // 16 MiB (1024 partial spectra)
    _Float16* vh    = (_Float16*)(ws + 130023424);    // 16 MiB
    _Float16* gbuf  = (_Float16*)(ws + 146800640);    // 16 MiB
    // q fp32 [B,H,DH,L] lives in d_out (exactly 32 MiB, rewritten by final GEMM)
    float*    qf32  = (float*)d_out;

    dim3 blk(256);

    prep_all<<<dim3(8704), blk, 0, stream>>>(x_q, x_kv, Wq, Wk, Wv, Wo,
                                             Xq_h, Xq_l, Xkv_h, Xkv_l,
                                             Wq_h, Wq_l, Wk_h, Wk_l, Wv_h, Wo_h);

    // merged q+k projections (hi/lo) -> fp32 [B,H,DH,L]; outputs disjoint
    gemm_qk<<<dim3(1024), blk, 0, stream>>>(Xq_h,  Xq_l,  Wq_h, Wq_l, bq, qf32,
                                            Xkv_h, Xkv_l, Wk_h, Wk_l, bk, kf32);

    // forward FFTs: 1024 blocks × 4 sequences -> 16 partials/bh (no atomics)
    fft_fwd<<<dim3(1024), blk, 0, stream>>>(qf32, kf32, specP);

    // merged inverse+top-8 (64 blocks) + v projection (512 blocks)
    inv_and_v<<<dim3(576), blk, 0, stream>>>(specP, dely, wgt, Xkv_h, Wv_h, bv, vh);

    // weighted circular gather -> fp16 [B,L,D]
    gather_ws<<<dim3(4096), blk, 0, stream>>>(vh, dely, wgt, gbuf);

    // final projection -> fp32 output (d_out; qf32 dead)
    gemm_o<<<dim3(512), blk, 0, stream>>>(gbuf, Wo_h, bo, out);
}

// Round 11
// 300.668 us; speedup vs baseline: 1.0229x; 1.0229x over previous
//
#include <hip/hip_runtime.h>
#include <math.h>

#define BB 8
#define LL 2048
#define DD 512
#define HH 8
#define DHH 64
#define KD 8
#define MM (BB*LL)   // 16384

typedef _Float16 f16x4 __attribute__((ext_vector_type(4)));
typedef _Float16 f16x8 __attribute__((ext_vector_type(8)));
typedef float    f32x4 __attribute__((ext_vector_type(4)));

// ---------------- prep: fp32 -> fp16 hi/lo (x and W fused in one launch) ----------------
__device__ inline void cvt8(const float* __restrict__ s, _Float16* hp, _Float16* lp) {
    const float4 a = *(const float4*)s;
    const float4 b = *(const float4*)(s + 4);
    const float v[8] = {a.x, a.y, a.z, a.w, b.x, b.y, b.z, b.w};
    f16x8 hi, lo;
#pragma unroll
    for (int j = 0; j < 8; j++) {
        const _Float16 h = (_Float16)v[j];
        hi[j] = h;
        lo[j] = (_Float16)((v[j] - (float)h) * 512.0f);
    }
    *(f16x8*)hp = hi;
    if (lp) *(f16x8*)lp = lo;
}

__global__ __launch_bounds__(256) void prep_all(const float* __restrict__ xq,
                                                const float* __restrict__ xkv,
                                                const float* __restrict__ Wq, const float* __restrict__ Wk,
                                                const float* __restrict__ Wv, const float* __restrict__ Wo,
                                                _Float16* __restrict__ Xq_h, _Float16* __restrict__ Xq_l,
                                                _Float16* __restrict__ Xkv_h, _Float16* __restrict__ Xkv_l,
                                                _Float16* __restrict__ Wq_h, _Float16* __restrict__ Wq_l,
                                                _Float16* __restrict__ Wk_h, _Float16* __restrict__ Wk_l,
                                                _Float16* __restrict__ Wv_h, _Float16* __restrict__ Wo_h) {
    const int bid = blockIdx.x;
    if (bid < 8192) {   // x_q / x_kv: 2097152 threads × 8 elems
        const int g = bid * 256 + threadIdx.x;
        const int which = g >> 20;
        const size_t idx = (size_t)(g & 1048575) * 8;
        const float* src = which ? xkv : xq;
        _Float16* dh = which ? Xkv_h : Xq_h;
        _Float16* dl = which ? Xkv_l : Xq_l;
        cvt8(src + idx, dh + idx, dl + idx);
    } else {            // weights: 131072 threads × 8 elems
        const int g = (bid - 8192) * 256 + threadIdx.x;
        const int which = g >> 15;
        const size_t idx = (size_t)(g & 32767) * 8;
        if (which == 0)      cvt8(Wq + idx, Wq_h + idx, Wq_l + idx);
        else if (which == 1) cvt8(Wk + idx, Wk_h + idx, Wk_l + idx);
        else if (which == 2) cvt8(Wv + idx, Wv_h + idx, nullptr);
        else                 cvt8(Wo + idx, Wo_h + idx, nullptr);
    }
}

// ---------------- MFMA GEMM body: C = A @ B^T + bias ----------------
// NPROD==1: plain (hi only). NPROD==3: hi/lo split (score path).
// MODE 0: fp32 C[m*512+n]
// MODE 1: fp32 C[(b*512+n)*2048+l]   (score path stays fp32 in storage)
// MODE 2: fp16 v-layout C[b,h,l,dh]
template<int NPROD, int MODE>
__device__ __forceinline__ void gemm_body(const _Float16* __restrict__ Ag,
                                          const _Float16* __restrict__ Al_g,
                                          const _Float16* __restrict__ Bg,
                                          const _Float16* __restrict__ Bl_g,
                                          const float* __restrict__ bias,
                                          void* __restrict__ Cv,
                                          _Float16* lds, int l0) {
    _Float16* Ah = lds;            // [128][40] halves, padded row stride
    _Float16* Bh = lds + 5120;
    _Float16* Al = (NPROD == 3) ? lds + 10240 : lds;
    _Float16* Bl = (NPROD == 3) ? lds + 15360 : lds;

    const int t  = threadIdx.x;
    const int m0 = (((l0 >> 5) << 3) | (l0 & 7)) * 128;   // XCD swizzle
    const int n0 = ((l0 >> 3) & 3) * 128;

    const int lrow = t >> 2;        // 0..63
    const int lcol = (t & 3) * 8;   // 0,8,16,24
    const int wave = t >> 6;
    const int lane = t & 63;
    const int wm   = (wave >> 1) * 64;
    const int wn   = (wave & 1) * 64;
    const int lm   = lane & 15;
    const int quad = lane >> 4;

    f32x4 acc0[4][4] = {};
    f32x4 acc1[4][4] = {};

    f16x8 pa[2], pb[2], pal[2], pbl[2];
#pragma unroll
    for (int p = 0; p < 2; p++) {
        pa[p] = *(const f16x8*)(Ag + (size_t)(m0 + p * 64 + lrow) * 512 + lcol);
        pb[p] = *(const f16x8*)(Bg + (size_t)(n0 + p * 64 + lrow) * 512 + lcol);
        if (NPROD == 3) {
            pal[p] = *(const f16x8*)(Al_g + (size_t)(m0 + p * 64 + lrow) * 512 + lcol);
            pbl[p] = *(const f16x8*)(Bl_g + (size_t)(n0 + p * 64 + lrow) * 512 + lcol);
        }
    }

    for (int k0 = 0; k0 < 512; k0 += 32) {
        __syncthreads();
#pragma unroll
        for (int p = 0; p < 2; p++) {
            const int row = p * 64 + lrow;
            *(f16x8*)&Ah[row * 40 + lcol] = pa[p];
            *(f16x8*)&Bh[row * 40 + lcol] = pb[p];
            if (NPROD == 3) {
                *(f16x8*)&Al[row * 40 + lcol] = pal[p];
                *(f16x8*)&Bl[row * 40 + lcol] = pbl[p];
            }
        }
        __syncthreads();

        if (k0 + 32 < 512) {
            const int kn = k0 + 32;
#pragma unroll
            for (int p = 0; p < 2; p++) {
                pa[p] = *(const f16x8*)(Ag + (size_t)(m0 + p * 64 + lrow) * 512 + kn + lcol);
                pb[p] = *(const f16x8*)(Bg + (size_t)(n0 + p * 64 + lrow) * 512 + kn + lcol);
                if (NPROD == 3) {
                    pal[p] = *(const f16x8*)(Al_g + (size_t)(m0 + p * 64 + lrow) * 512 + kn + lcol);
                    pbl[p] = *(const f16x8*)(Bl_g + (size_t)(n0 + p * 64 + lrow) * 512 + kn + lcol);
                }
            }
        }

        f16x8 afh[4], bf[4];
#pragma unroll
        for (int mt = 0; mt < 4; mt++)
            afh[mt] = *(f16x8*)&Ah[(wm + mt * 16 + lm) * 40 + quad * 8];
#pragma unroll
        for (int nt = 0; nt < 4; nt++)
            bf[nt] = *(f16x8*)&Bh[(wn + nt * 16 + lm) * 40 + quad * 8];

#pragma unroll
        for (int mt = 0; mt < 4; mt++)
#pragma unroll
            for (int nt = 0; nt < 4; nt++)
                acc0[mt][nt] = __builtin_amdgcn_mfma_f32_16x16x32_f16(afh[mt], bf[nt], acc0[mt][nt], 0, 0, 0);

        if (NPROD == 3) {
            f16x8 afl[4];
#pragma unroll
            for (int mt = 0; mt < 4; mt++)
                afl[mt] = *(f16x8*)&Al[(wm + mt * 16 + lm) * 40 + quad * 8];
#pragma unroll
            for (int mt = 0; mt < 4; mt++)
#pragma unroll
                for (int nt = 0; nt < 4; nt++)
                    acc1[mt][nt] = __builtin_amdgcn_mfma_f32_16x16x32_f16(afl[mt], bf[nt], acc1[mt][nt], 0, 0, 0);
#pragma unroll
            for (int nt = 0; nt < 4; nt++)
                bf[nt] = *(f16x8*)&Bl[(wn + nt * 16 + lm) * 40 + quad * 8];
#pragma unroll
            for (int mt = 0; mt < 4; mt++)
#pragma unroll
                for (int nt = 0; nt < 4; nt++)
                    acc1[mt][nt] = __builtin_amdgcn_mfma_f32_16x16x32_f16(afh[mt], bf[nt], acc1[mt][nt], 0, 0, 0);
        }
    }

    // epilogue: C/D layout col=lane&15, row=quad*4+reg
#pragma unroll
    for (int mt = 0; mt < 4; mt++) {
#pragma unroll
        for (int nt = 0; nt < 4; nt++) {
            const int n = n0 + wn + nt * 16 + lm;
            const float bv = bias[n];
            float val[4];
#pragma unroll
            for (int r = 0; r < 4; r++) {
                val[r] = acc0[mt][nt][r] + bv;
                if (NPROD == 3) val[r] += acc1[mt][nt][r] * (1.0f / 512.0f);
            }
            const int mbase = m0 + wm + mt * 16 + quad * 4;   // multiple of 4
            const int b_idx = mbase >> 11;
            const int lbase = mbase & 2047;
            if (MODE == 0) {
                float* C = (float*)Cv;
#pragma unroll
                for (int r = 0; r < 4; r++) C[(size_t)(mbase + r) * 512 + n] = val[r];
            } else if (MODE == 1) {
                float* C = (float*)Cv;
                float4 pv = make_float4(val[0], val[1], val[2], val[3]);
                *(float4*)&C[((size_t)(b_idx * 512 + n)) * 2048 + lbase] = pv;
            } else {
                _Float16* C = (_Float16*)Cv;
#pragma unroll
                for (int r = 0; r < 4; r++)
                    C[(size_t)b_idx * 1048576 + (size_t)(n >> 6) * 131072
                      + (size_t)(lbase + r) * 64 + (n & 63)] = (_Float16)val[r];
            }
        }
    }
}

// merged q+k projection: 1024 blocks; 0-511 = q, 512-1023 = k (disjoint outputs)
__global__ __launch_bounds__(256, 2) void gemm_qk(const _Float16* __restrict__ A0h, const _Float16* __restrict__ A0l,
                                                  const _Float16* __restrict__ B0h, const _Float16* __restrict__ B0l,
                                                  const float* __restrict__ bias0, float* __restrict__ C0,
                                                  const _Float16* __restrict__ A1h, const _Float16* __restrict__ A1l,
                                                  const _Float16* __restrict__ B1h, const _Float16* __restrict__ B1l,
                                                  const float* __restrict__ bias1, float* __restrict__ C1) {
    __shared__ __align__(16) _Float16 lds[20480];
    const int prob = blockIdx.x >> 9;
    const int l0   = blockIdx.x & 511;
    if (prob == 0)
        gemm_body<3, 1>(A0h, A0l, B0h, B0l, bias0, C0, lds, l0);
    else
        gemm_body<3, 1>(A1h, A1l, B1h, B1l, bias1, C1, lds, l0);
}

__global__ __launch_bounds__(256, 2) void gemm_v(const _Float16* __restrict__ Ah_g,
                                                 const _Float16* __restrict__ Bh_g,
                                                 const float* __restrict__ bias,
                                                 _Float16* __restrict__ C) {
    __shared__ __align__(16) _Float16 lds[10240];
    gemm_body<1, 2>(Ah_g, Ah_g, Bh_g, Bh_g, bias, C, lds, blockIdx.x);
}

__global__ __launch_bounds__(256, 2) void gemm_o(const _Float16* __restrict__ Ah_g,
                                                 const _Float16* __restrict__ Bh_g,
                                                 const float* __restrict__ bias,
                                                 float* __restrict__ C) {
    __shared__ __align__(16) _Float16 lds[10240];
    gemm_body<1, 0>(Ah_g, Ah_g, Bh_g, Bh_g, bias, C, lds, blockIdx.x);
}

// ============== register-resident radix-8 DIF forward FFT (N=2048), fp32 in ==============
// STANDALONE kernel, source-identical to round 9's (passed) — score-path codegen
// is fragile (round-10 post-mortem): do NOT repackage this kernel.
#define PAD3(i) ((i) + ((i) >> 3))

__device__ inline float2 cmul2(float2 a, float2 w) {
    return make_float2(a.x * w.x - a.y * w.y, a.x * w.y + a.y * w.x);
}
__device__ inline float2 cadd2(float2 a, float2 b) { return make_float2(a.x + b.x, a.y + b.y); }
__device__ inline float2 csub2(float2 a, float2 b) { return make_float2(a.x - b.x, a.y - b.y); }

__global__ __launch_bounds__(256) void fft_fwd(const float* __restrict__ qT,
                                               const float* __restrict__ kT,
                                               float* __restrict__ specP) {
    const int blk  = blockIdx.x;     // bh*16 + part
    const int bh   = blk >> 4;
    const int part = blk & 15;
    const int t    = threadIdx.x;
    __shared__ float2 Zs[2304];      // PAD3(2047) = 2302
    __shared__ float2 Wt[1024];      // Wt[j] = exp(-2*pi*i*j/2048)

#pragma unroll
    for (int s = 0; s < 4; s++) {
        const int j = t + s * 256;
        float sv, cv;
        __sincosf(2.0f * (float)M_PI * (float)j / 2048.0f, &sv, &cv);
        Wt[j] = make_float2(cv, -sv);
    }

    float2 pacc[8];
#pragma unroll
    for (int s = 0; s < 8; s++) pacc[s] = make_float2(0.0f, 0.0f);

    const int low5 = t & 31, hi3 = t >> 5;
    const int low2 = t & 3,  hi6 = t >> 2;

    for (int j4 = 0; j4 < 4; j4++) {
        const int seq = bh * 64 + part * 4 + j4;
        const float* qp = qT + (size_t)seq * 2048;
        const float* kp = kT + (size_t)seq * 2048;
        float2 z[8];
#pragma unroll
        for (int s = 0; s < 8; s++) z[s] = make_float2(qp[t + 256 * s], kp[t + 256 * s]);
        __syncthreads();   // Wt ready (iter 0); prev unpack reads done (iter >0)

        // round 1 (bits 10,9,8), jb = t
#pragma unroll
        for (int sp = 0; sp < 4; sp++) {
            float2 u = z[sp], v = z[sp + 4];
            z[sp]     = cadd2(u, v);
            z[sp + 4] = cmul2(csub2(u, v), Wt[t + 256 * sp]);
        }
#pragma unroll
        for (int base = 0; base < 8; base += 4)
#pragma unroll
            for (int q2 = 0; q2 < 2; q2++) {
                float2 u = z[base + q2], v = z[base + q2 + 2];
                z[base + q2]     = cadd2(u, v);
                z[base + q2 + 2] = cmul2(csub2(u, v), Wt[2 * (t + 256 * q2)]);
            }
        {
            const float2 w = Wt[4 * t];
#pragma unroll
            for (int e = 0; e < 8; e += 2) {
                float2 u = z[e], v = z[e + 1];
                z[e]     = cadd2(u, v);
                z[e + 1] = cmul2(csub2(u, v), w);
            }
        }

        // exchange 1: (t+256s) -> (low5+32s+256hi3)
#pragma unroll
        for (int s = 0; s < 8; s++) Zs[PAD3(t + 256 * s)] = z[s];
        __syncthreads();
#pragma unroll
        for (int s = 0; s < 8; s++) z[s] = Zs[PAD3(low5 + 32 * s + 256 * hi3)];
        // no barrier: round-2 writes return to the same slots this thread read

        // round 2 (bits 7,6,5), jb = low5
#pragma unroll
        for (int sp = 0; sp < 4; sp++) {
            float2 u = z[sp], v = z[sp + 4];
            z[sp]     = cadd2(u, v);
            z[sp + 4] = cmul2(csub2(u, v), Wt[8 * (low5 + 32 * sp)]);
        }
#pragma unroll
        for (int base = 0; base < 8; base += 4)
#pragma unroll
            for (int q2 = 0; q2 < 2; q2++) {
                float2 u = z[base + q2], v = z[base + q2 + 2];
                z[base + q2]     = cadd2(u, v);
                z[base + q2 + 2] = cmul2(csub2(u, v), Wt[16 * (low5 + 32 * q2)]);
            }
        {
            const float2 w = Wt[32 * low5];
#pragma unroll
            for (int e = 0; e < 8; e += 2) {
                float2 u = z[e], v = z[e + 1];
                z[e]     = cadd2(u, v);
                z[e + 1] = cmul2(csub2(u, v), w);
            }
        }

        // exchange 2: (low5+32s+256hi3) -> (low2+4s+32hi6)
#pragma unroll
        for (int s = 0; s < 8; s++) Zs[PAD3(low5 + 32 * s + 256 * hi3)] = z[s];
        __syncthreads();
#pragma unroll
        for (int s = 0; s < 8; s++) z[s] = Zs[PAD3(low2 + 4 * s + 32 * hi6)];

        // round 3 (bits 4,3,2), jb = low2
#pragma unroll
        for (int sp = 0; sp < 4; sp++) {
            float2 u = z[sp], v = z[sp + 4];
            z[sp]     = cadd2(u, v);
            z[sp + 4] = cmul2(csub2(u, v), Wt[64 * (low2 + 4 * sp)]);
        }
#pragma unroll
        for (int base = 0; base < 8; base += 4)
#pragma unroll
            for (int q2 = 0; q2 < 2; q2++) {
                float2 u = z[base + q2], v = z[base + q2 + 2];
                z[base + q2]     = cadd2(u, v);
                z[base + q2 + 2] = cmul2(csub2(u, v), Wt[128 * (low2 + 4 * q2)]);
            }
        {
            const float2 w = Wt[256 * low2];
#pragma unroll
            for (int e = 0; e < 8; e += 2) {
                float2 u = z[e], v = z[e + 1];
                z[e]     = cadd2(u, v);
                z[e + 1] = cmul2(csub2(u, v), w);
            }
        }

        // exchange 3: (low2+4s+32hi6) -> (8t+s)
#pragma unroll
        for (int s = 0; s < 8; s++) Zs[PAD3(low2 + 4 * s + 32 * hi6)] = z[s];
        __syncthreads();
#pragma unroll
        for (int s = 0; s < 8; s++) z[s] = Zs[PAD3(8 * t + s)];

        // round 4 (bits 1,0)
#pragma unroll
        for (int base = 0; base < 8; base += 4) {
            {
                float2 u = z[base], v = z[base + 2];
                z[base]     = cadd2(u, v);
                z[base + 2] = csub2(u, v);
            }
            {
                float2 u = z[base + 1], v = z[base + 3];
                float2 d = csub2(u, v);
                z[base + 1] = cadd2(u, v);
                z[base + 3] = make_float2(d.y, -d.x);
            }
        }
#pragma unroll
        for (int e = 0; e < 8; e += 2) {
            float2 u = z[e], v = z[e + 1];
            z[e]     = cadd2(u, v);
            z[e + 1] = csub2(u, v);
        }

        // write back completed FFT (same slots this thread read -> only one barrier)
#pragma unroll
        for (int s = 0; s < 8; s++) Zs[PAD3(8 * t + s)] = z[s];
        __syncthreads();

        // unpack q+ik; accumulate P at thread-fixed positions p = t+256s (registers)
#pragma unroll
        for (int s = 0; s < 8; s++) {
            const int p  = t + 256 * s;
            const int f  = (int)(__brev((unsigned)p) >> 21);
            const int fm = (2048 - f) & 2047;
            const int p2 = (int)(__brev((unsigned)fm) >> 21);
            const float2 zf = Zs[PAD3(p)];
            const float2 zm = Zs[PAD3(p2)];
            const float qr = 0.5f * (zf.x + zm.x);
            const float qi = 0.5f * (zf.y - zm.y);
            const float kr = 0.5f * (zf.y + zm.y);
            const float ki = 0.5f * (zm.x - zf.x);
            if (f != 0) {   // DC bin stays zero (mean subtraction)
                pacc[s].x += qr * kr + qi * ki;
                pacc[s].y += qi * kr - qr * ki;
            }
        }
    }

    // one coalesced partial-spectrum store (bit-rev position order)
    float2* outp = (float2*)specP + (size_t)blk * 2048;
#pragma unroll
    for (int s = 0; s < 8; s++) outp[t + 256 * s] = pacc[s];
}

// ---------------- inverse (DIT over bit-reversed input) + top-8, standalone ----------------
// Source-identical to round 8's (passed). Do NOT repackage.
__device__ inline void build_twiddle(float2* Wt, int tid, float sign) {
#pragma unroll
    for (int s = 0; s < 4; s++) {
        const int j = tid + s * 256;
        const float a = 2.0f * (float)M_PI * (float)j / 2048.0f;
        float sv, cv;
        __sincosf(a, &sv, &cv);
        Wt[j] = make_float2(cv, sign * sv);
    }
}

__device__ inline void fft2048_stages(float2* Z, const float2* Wt, int tid) {
    for (int st = 0; st < 11; st++) {
        const int half = 1 << st;
        const int shift = 10 - st;
#pragma unroll
        for (int r = 0; r < 4; r++) {
            const int m   = tid + r * 256;
            const int grp = m >> st;
            const int pos = m & (half - 1);
            const int i0  = (grp << (st + 1)) + pos;
            const int i1  = i0 + half;
            const float2 w = Wt[pos << shift];
            const float2 a = Z[i0];
            const float2 b = Z[i1];
            const float tr = b.x * w.x - b.y * w.y;
            const float ti = b.x * w.y + b.y * w.x;
            Z[i0] = make_float2(a.x + tr, a.y + ti);
            Z[i1] = make_float2(a.x - tr, a.y - ti);
        }
        __syncthreads();
    }
}

__global__ __launch_bounds__(256) void fft_inv_topk(const float* __restrict__ specP,
                                                    int* __restrict__ delays,
                                                    float* __restrict__ weights) {
    const int bh  = blockIdx.x;
    const int tid = threadIdx.x;
    __shared__ float2 Z[2048];
    __shared__ float2 Wt[1024];
    __shared__ float  corrS[2048];
    __shared__ float  rv[256];
    __shared__ int    ri[256];
    __shared__ float  vals[KD];
    __shared__ int    inds[KD];

    build_twiddle(Wt, tid, +1.0f);

    const float2* sp = (const float2*)specP + (size_t)bh * 16 * 2048;
#pragma unroll
    for (int s = 0; s < 8; s++) {
        const int p = tid + s * 256;
        float2 acc = make_float2(0.0f, 0.0f);
#pragma unroll
        for (int part = 0; part < 16; part++) {
            const float2 v = sp[part * 2048 + p];
            acc.x += v.x; acc.y += v.y;
        }
        Z[p] = acc;
    }
    __syncthreads();
    fft2048_stages(Z, Wt, tid);

    const float scale = 1.0f / (2048.0f * 64.0f);
#pragma unroll
    for (int s = 0; s < 8; s++) {
        const int i = tid + s * 256;
        corrS[i] = Z[i].x * scale;
    }
    __syncthreads();

    for (int k = 0; k < KD; k++) {
        float best = -1e30f;
        int   bi   = 1 << 30;
        for (int i = tid; i < 2048; i += 256) {
            const float v = corrS[i];
            if (v > best || (v == best && i < bi)) { best = v; bi = i; }
        }
        rv[tid] = best;
        ri[tid] = bi;
        __syncthreads();
        for (int off = 128; off > 0; off >>= 1) {
            if (tid < off) {
                const float v2 = rv[tid + off];
                const int   i2 = ri[tid + off];
                if (v2 > rv[tid] || (v2 == rv[tid] && i2 < ri[tid])) {
                    rv[tid] = v2; ri[tid] = i2;
                }
            }
            __syncthreads();
        }
        if (tid == 0) {
            vals[k] = rv[0];
            inds[k] = ri[0];
            corrS[ri[0]] = -1e30f;
        }
        __syncthreads();
    }

    if (tid == 0) {
        float sum = 0.0f;
        for (int k = 0; k < KD; k++) sum += vals[k];
        const float inv = 1.0f / (sum + 1e-12f);
        for (int k = 0; k < KD; k++) {
            weights[bh * KD + k] = vals[k] * inv;
            delays[bh * KD + k]  = inds[k];
        }
    }
}

// weighted circular-shift gather, fp16 in/out, 8 dh per thread (16B loads/stores)
__global__ __launch_bounds__(256) void gather_ws(const _Float16* __restrict__ v,
                                                 const int* __restrict__ delays,
                                                 const float* __restrict__ weights,
                                                 _Float16* __restrict__ outb) {
    const int gp = blockIdx.x * 256 + threadIdx.x;   // over M*64 = 1048576
    const int c8 = gp & 63;
    const int m  = gp >> 6;
    const int l  = m & 2047;
    const int b  = m >> 11;
    const int ch = c8 * 8;
    const int h  = ch >> 6;
    const int dh = ch & 63;
    const int bh = b * 8 + h;

    const _Float16* vb = v + (size_t)bh * 131072;
    float a[8] = {};
#pragma unroll
    for (int k = 0; k < KD; k++) {
        const int   d = delays[bh * KD + k];
        const float w = weights[bh * KD + k];
        const int   p = (l + d) & 2047;
        const f16x8 pv = *(const f16x8*)&vb[p * 64 + dh];
#pragma unroll
        for (int j = 0; j < 8; j++) a[j] = fmaf(w, (float)pv[j], a[j]);
    }
    f16x8 ov;
#pragma unroll
    for (int j = 0; j < 8; j++) ov[j] = (_Float16)a[j];
    *(f16x8*)&outb[(size_t)m * 512 + ch] = ov;
}

extern "C" void kernel_launch(void* const* d_in, const int* in_sizes, int n_in,
                              void* d_out, int out_size, void* d_ws, size_t ws_size,
                              hipStream_t stream) {
    const float* x_q  = (const float*)d_in[0];
    const float* x_kv = (const float*)d_in[1];
    const float* Wq   = (const float*)d_in[2];
    const float* bq   = (const float*)d_in[3];
    const float* Wk   = (const float*)d_in[4];
    const float* bk   = (const float*)d_in[5];
    const float* Wv   = (const float*)d_in[6];
    const float* bv   = (const float*)d_in[7];
    const float* Wo   = (const float*)d_in[8];
    const float* bo   = (const float*)d_in[9];
    float* out = (float*)d_out;

    // ---- workspace layout: d_ws is 256 MiB (fill-counter evidence, round 8);
    //      fully unaliased plan, peak use 156 MiB ----
    char* ws = (char*)d_ws;
    _Float16* Xq_h  = (_Float16*)(ws + 0);            // 16 MiB
    _Float16* Xq_l  = (_Float16*)(ws + 16777216);     // 16 MiB
    _Float16* Xkv_h = (_Float16*)(ws + 33554432);     // 16 MiB
    _Float16* Xkv_l = (_Float16*)(ws + 50331648);     // 16 MiB
    _Float16* Wq_h  = (_Float16*)(ws + 67108864);     // 512 KiB each
    _Float16* Wq_l  = (_Float16*)(ws + 67633152);
    _Float16* Wk_h  = (_Float16*)(ws + 68157440);
    _Float16* Wk_l  = (_Float16*)(ws + 68681728);
    _Float16* Wv_h  = (_Float16*)(ws + 69206016);
    _Float16* Wo_h  = (_Float16*)(ws + 69730304);
    int*      dely  = (int*)    (ws + 70254592);
    float*    wgt   = (float*)  (ws + 70256640);
    float*    kf32  = (float*)  (ws + 75497472);      // 32 MiB, disjoint from all GEMM inputs
    float*    specP = (float*)  (ws + 113246208);     // 16 MiB (1024 partial spectra)
    _Float16* vh    = (_Float16*)(ws + 130023424);    // 16 MiB
    _Float16* gbuf  = (_Float16*)(ws + 146800640);    // 16 MiB
    // q fp32 [B,H,DH,L] lives in d_out (exactly 32 MiB, rewritten by final GEMM)
    float*    qf32  = (float*)d_out;

    dim3 blk(256);

    prep_all<<<dim3(8704), blk, 0, stream>>>(x_q, x_kv, Wq, Wk, Wv, Wo,
                                             Xq_h, Xq_l, Xkv_h, Xkv_l,
                                             Wq_h, Wq_l, Wk_h, Wk_l, Wv_h, Wo_h);

    // merged q+k projections (hi/lo) -> fp32 [B,H,DH,L]; outputs disjoint
    gemm_qk<<<dim3(1024), blk, 0, stream>>>(Xq_h,  Xq_l,  Wq_h, Wq_l, bq, qf32,
                                            Xkv_h, Xkv_l, Wk_h, Wk_l, bk, kf32);

    // forward FFTs: standalone (frozen codegen — score path)
    fft_fwd<<<dim3(1024), blk, 0, stream>>>(qf32, kf32, specP);

    // inverse + top-8: standalone (frozen codegen — score path)
    fft_inv_topk<<<dim3(BB * HH), blk, 0, stream>>>(specP, dely, wgt);

    // v projection (plain fp16) -> fp16 [B,H,L,DH]
    gemm_v<<<dim3(512), blk, 0, stream>>>(Xkv_h, Wv_h, bv, vh);

    // weighted circular gather -> fp16 [B,L,D]
    gather_ws<<<dim3(4096), blk, 0, stream>>>(vh, dely, wgt, gbuf);

    // final projection -> fp32 output (d_out; qf32 dead)
    gemm_o<<<dim3(512), blk, 0, stream>>>(gbuf, Wo_h, bo, out);
}